// Round 1
// baseline (1271.059 us; speedup 1.0000x reference)
//
#include <hip/hip_runtime.h>
#include <math.h>

#define BB 4
#define SS 2048
#define DD 512
#define NH 8
#define HD 64

// ---------------- GEMM: q[M=8192, N=512] = x[8192,512] @ Wq[512,512] ----------------
__global__ __launch_bounds__(256) void gemm_kernel(const float* __restrict__ x,
                                                   const float* __restrict__ w,
                                                   float* __restrict__ q) {
    __shared__ float As[64][17];   // +1 pad: breaks 4-way bank conflict on column reads
    __shared__ float Bs[16][64];
    const int tid = threadIdx.x;
    const int bm = blockIdx.x;     // 0..127
    const int bn = blockIdx.y;     // 0..7
    const int tx = tid & 15, ty = tid >> 4;
    const int M0 = bm * 64, N0 = bn * 64;
    float acc[4][4] = {};

    for (int k0 = 0; k0 < 512; k0 += 16) {
        // A tile 64x16: thread loads one float4
        {
            int row = tid >> 2;
            int c4  = (tid & 3) * 4;
            const float4 v = *(const float4*)(x + (size_t)(M0 + row) * 512 + k0 + c4);
            As[row][c4 + 0] = v.x; As[row][c4 + 1] = v.y;
            As[row][c4 + 2] = v.z; As[row][c4 + 3] = v.w;
        }
        // B tile 16x64
        {
            int row = tid >> 4;
            int c4  = (tid & 15) * 4;
            *(float4*)&Bs[row][c4] = *(const float4*)(w + (size_t)(k0 + row) * 512 + N0 + c4);
        }
        __syncthreads();
        #pragma unroll
        for (int kk = 0; kk < 16; ++kk) {
            float a[4], b[4];
            #pragma unroll
            for (int i = 0; i < 4; ++i) a[i] = As[ty * 4 + i][kk];
            #pragma unroll
            for (int j = 0; j < 4; ++j) b[j] = Bs[kk][tx * 4 + j];
            #pragma unroll
            for (int i = 0; i < 4; ++i)
                #pragma unroll
                for (int j = 0; j < 4; ++j)
                    acc[i][j] += a[i] * b[j];
        }
        __syncthreads();
    }
    #pragma unroll
    for (int i = 0; i < 4; ++i) {
        float4 v = { acc[i][0], acc[i][1], acc[i][2], acc[i][3] };
        *(float4*)(q + (size_t)(M0 + ty * 4 + i) * 512 + N0 + tx * 4) = v;
    }
}

// ---------------- Attention: out = softmax(q qT / 8) q, per (b, head) ----------------
// One thread = one query row. No max-subtraction needed: scores bounded ~15,
// exp(15)=3.3e6 and sums < 1e10, safely inside fp32 range; normalization o/l exact.
__global__ __launch_bounds__(256) void attn_kernel(const float* __restrict__ q,
                                                   float* __restrict__ out) {
    __shared__ float Ks[64][64];   // broadcast reads only -> conflict-free
    const int tid = threadIdx.x;
    const int bid = blockIdx.x;    // 256 blocks = 4(b) * 8(h) * 8(qblock)
    const int qb = bid & 7;
    const int h  = (bid >> 3) & 7;
    const int b  = bid >> 6;
    const float* qbh = q + (size_t)b * SS * DD + h * HD;
    const int row = qb * 256 + tid;

    float qr[HD];
    #pragma unroll
    for (int j4 = 0; j4 < 16; ++j4) {
        float4 v = *(const float4*)(qbh + (size_t)row * DD + j4 * 4);
        qr[j4 * 4 + 0] = v.x; qr[j4 * 4 + 1] = v.y;
        qr[j4 * 4 + 2] = v.z; qr[j4 * 4 + 3] = v.w;
    }
    float o[HD] = {};
    float l = 0.f;

    for (int kb = 0; kb < SS; kb += 64) {
        __syncthreads();   // protect Ks from previous iteration's readers
        #pragma unroll
        for (int i = 0; i < 4; ++i) {
            int f  = tid + 256 * i;        // 0..1023
            int kr = f >> 4;               // 0..63
            int c4 = (f & 15) * 4;         // 0..60
            *(float4*)&Ks[kr][c4] = *(const float4*)(qbh + (size_t)(kb + kr) * DD + c4);
        }
        __syncthreads();

        #pragma unroll 1
        for (int k = 0; k < 64; ++k) {
            float s0 = 0.f, s1 = 0.f, s2 = 0.f, s3 = 0.f;  // 4 chains for FMA ILP
            #pragma unroll
            for (int j = 0; j < 16; ++j) {
                s0 += qr[j * 4 + 0] * Ks[k][j * 4 + 0];
                s1 += qr[j * 4 + 1] * Ks[k][j * 4 + 1];
                s2 += qr[j * 4 + 2] * Ks[k][j * 4 + 2];
                s3 += qr[j * 4 + 3] * Ks[k][j * 4 + 3];
            }
            const float p = __expf(((s0 + s1) + (s2 + s3)) * 0.125f);
            l += p;
            #pragma unroll
            for (int j = 0; j < HD; ++j) o[j] += p * Ks[k][j];
        }
    }

    const float inv = 1.f / l;
    float* op = out + (size_t)b * SS * DD + (size_t)row * DD + h * HD;
    #pragma unroll
    for (int j4 = 0; j4 < 16; ++j4) {
        float4 v = { o[j4 * 4 + 0] * inv, o[j4 * 4 + 1] * inv,
                     o[j4 * 4 + 2] * inv, o[j4 * 4 + 3] * inv };
        *(float4*)(op + j4 * 4) = v;
    }
}

extern "C" void kernel_launch(void* const* d_in, const int* in_sizes, int n_in,
                              void* d_out, int out_size, void* d_ws, size_t ws_size,
                              hipStream_t stream) {
    const float* x  = (const float*)d_in[0];
    const float* wq = (const float*)d_in[1];
    float* out = (float*)d_out;
    float* q   = (float*)d_ws;   // 8192*512 floats = 16 MB

    dim3 ggrid(128, 8);
    gemm_kernel<<<ggrid, 256, 0, stream>>>(x, wq, q);
    attn_kernel<<<256, 256, 0, stream>>>(q, out);
}

// Round 2
// 194.922 us; speedup vs baseline: 6.5209x; 6.5209x over previous
//
#include <hip/hip_runtime.h>
#include <hip/hip_bf16.h>
#include <math.h>

#define SS 2048
#define DD 512
#define NH 8
#define HD 64

typedef __attribute__((ext_vector_type(8))) short frag_ab;   // 8 bf16
typedef __attribute__((ext_vector_type(4))) float frag_cd;   // 4 fp32

static __device__ inline unsigned int pack_bf16(float x, float y) {
    __hip_bfloat162 t = __float22bfloat162_rn(make_float2(x, y));  // x -> low
    return *(unsigned int*)&t;
}

// ---------------- GEMM: q_bf[8192,512] = bf16( x[8192,512] @ Wq[512,512] ) ----------------
__global__ __launch_bounds__(256) void gemm_kernel(const float* __restrict__ x,
                                                   const float* __restrict__ w,
                                                   __hip_bfloat16* __restrict__ q) {
    __shared__ float As[64][17];
    __shared__ float Bs[16][64];
    const int tid = threadIdx.x;
    const int bm = blockIdx.x, bn = blockIdx.y;
    const int tx = tid & 15, ty = tid >> 4;
    const int M0 = bm * 64, N0 = bn * 64;
    float acc[4][4] = {};

    for (int k0 = 0; k0 < 512; k0 += 16) {
        {
            int row = tid >> 2, c4 = (tid & 3) * 4;
            const float4 v = *(const float4*)(x + (size_t)(M0 + row) * 512 + k0 + c4);
            As[row][c4 + 0] = v.x; As[row][c4 + 1] = v.y;
            As[row][c4 + 2] = v.z; As[row][c4 + 3] = v.w;
        }
        {
            int row = tid >> 4, c4 = (tid & 15) * 4;
            *(float4*)&Bs[row][c4] = *(const float4*)(w + (size_t)(k0 + row) * 512 + N0 + c4);
        }
        __syncthreads();
        #pragma unroll
        for (int kk = 0; kk < 16; ++kk) {
            float a[4], b[4];
            #pragma unroll
            for (int i = 0; i < 4; ++i) a[i] = As[ty * 4 + i][kk];
            #pragma unroll
            for (int j = 0; j < 4; ++j) b[j] = Bs[kk][tx * 4 + j];
            #pragma unroll
            for (int i = 0; i < 4; ++i)
                #pragma unroll
                for (int j = 0; j < 4; ++j)
                    acc[i][j] += a[i] * b[j];
        }
        __syncthreads();
    }
    #pragma unroll
    for (int i = 0; i < 4; ++i) {
        uint2 p = { pack_bf16(acc[i][0], acc[i][1]), pack_bf16(acc[i][2], acc[i][3]) };
        *(uint2*)((unsigned short*)q + (size_t)(M0 + ty * 4 + i) * 512 + N0 + tx * 4) = p;
    }
}

// ---------------- Flash attention, MFMA bf16, no online rescale needed ----------------
// Scores s = q.k/8 are bounded (|s| <~ 16): exp and the running sum over 2048 keys stay
// far inside fp32 range, so we accumulate unnormalized O and l and divide once.
__global__ __launch_bounds__(256, 2) void attn_kernel(const __hip_bfloat16* __restrict__ qg,
                                                      float* __restrict__ out) {
    // key-major K tile (stride 72 bf16 = 144 B: rows 16B-aligned, ~2-way banks)
    __shared__ __align__(16) unsigned short Kt[64 * 72];
    // feature-major V^T tile
    __shared__ __align__(16) unsigned short Vt[64 * 72];
    // per-wave P stage: P[q_local 0..15][key 0..63]
    __shared__ __align__(16) unsigned short Pq[4][16 * 72];

    const int tid  = threadIdx.x;
    const int lane = tid & 63;
    const int wv   = tid >> 6;
    const int a    = lane & 15;   // n-index: this lane's q column
    const int g    = lane >> 4;   // k-group

    const int bid = blockIdx.x;          // 1024 = 4(b) * 8(h) * 32(qt)
    const int qt  = bid & 31;
    const int h   = (bid >> 5) & 7;
    const int b   = bid >> 8;

    const unsigned short* qbh = (const unsigned short*)qg + (size_t)b * SS * DD + h * HD;

    // Q B-fragments (kept in registers): lane holds Q[q=a][f = g*8+32*half + j]
    const int qrow = qt * 64 + wv * 16 + a;
    const frag_ab qf0 = *(const frag_ab*)(qbh + (size_t)qrow * DD + g * 8);
    const frag_ab qf1 = *(const frag_ab*)(qbh + (size_t)qrow * DD + 32 + g * 8);

    frag_cd oacc[4] = {};   // O^T tiles: ft*16 features x 16 queries
    float l_acc = 0.f;

    // staging map: thread -> 8 keys x 2 features
    const int f0 = (tid & 31) * 2;
    const int r0 = (tid >> 5) * 8;
    unsigned short* myP = Pq[wv];

    for (int kb = 0; kb < SS; kb += 64) {
        __syncthreads();                       // previous tile fully consumed
        unsigned int d[8];
        #pragma unroll
        for (int k = 0; k < 8; ++k)
            d[k] = *(const unsigned int*)(qbh + (size_t)(kb + r0 + k) * DD + f0);
        #pragma unroll
        for (int k = 0; k < 8; ++k)            // key-major copy
            *(unsigned int*)(&Kt[(r0 + k) * 72 + f0]) = d[k];
        {                                      // feature-major (transposed) copy
            unsigned int vlo[4], vhi[4];
            #pragma unroll
            for (int j = 0; j < 4; ++j) {
                vlo[j] = (d[2 * j] & 0xFFFFu) | (d[2 * j + 1] << 16);
                vhi[j] = (d[2 * j] >> 16)     | (d[2 * j + 1] & 0xFFFF0000u);
            }
            *(uint4*)(&Vt[(f0 + 0) * 72 + r0]) = make_uint4(vlo[0], vlo[1], vlo[2], vlo[3]);
            *(uint4*)(&Vt[(f0 + 1) * 72 + r0]) = make_uint4(vhi[0], vhi[1], vhi[2], vhi[3]);
        }
        __syncthreads();

        // ---- S^T = K . Q^T : 4 tiles of (16 keys x 16 queries) ----
        frag_cd st[4];
        #pragma unroll
        for (int kt = 0; kt < 4; ++kt) {
            const frag_ab ka0 = *(const frag_ab*)(&Kt[(kt * 16 + a) * 72 + g * 8]);
            const frag_ab ka1 = *(const frag_ab*)(&Kt[(kt * 16 + a) * 72 + 32 + g * 8]);
            frag_cd c = {};
            c = __builtin_amdgcn_mfma_f32_16x16x32_bf16(ka0, qf0, c, 0, 0, 0);
            c = __builtin_amdgcn_mfma_f32_16x16x32_bf16(ka1, qf1, c, 0, 0, 0);
            st[kt] = c;
        }
        // ---- exp, l accumulate, stage P (lane's 4 values are key-consecutive) ----
        #pragma unroll
        for (int kt = 0; kt < 4; ++kt) {
            const float p0 = __expf(st[kt][0] * 0.125f);
            const float p1 = __expf(st[kt][1] * 0.125f);
            const float p2 = __expf(st[kt][2] * 0.125f);
            const float p3 = __expf(st[kt][3] * 0.125f);
            l_acc += (p0 + p1) + (p2 + p3);
            uint2 pw = { pack_bf16(p0, p1), pack_bf16(p2, p3) };
            *(uint2*)(&myP[a * 72 + kt * 16 + g * 4]) = pw;   // wave-private: no barrier
        }
        // ---- O^T += V^T . P^T ----
        const frag_ab pb0 = *(const frag_ab*)(&myP[a * 72 + g * 8]);
        const frag_ab pb1 = *(const frag_ab*)(&myP[a * 72 + 32 + g * 8]);
        #pragma unroll
        for (int ft = 0; ft < 4; ++ft) {
            const frag_ab va0 = *(const frag_ab*)(&Vt[(ft * 16 + a) * 72 + g * 8]);
            const frag_ab va1 = *(const frag_ab*)(&Vt[(ft * 16 + a) * 72 + 32 + g * 8]);
            oacc[ft] = __builtin_amdgcn_mfma_f32_16x16x32_bf16(va0, pb0, oacc[ft], 0, 0, 0);
            oacc[ft] = __builtin_amdgcn_mfma_f32_16x16x32_bf16(va1, pb1, oacc[ft], 0, 0, 0);
        }
    }

    // l: lane has partial sum for q=a over its key subset; reduce across the 4 k-groups
    l_acc += __shfl_xor(l_acc, 16, 64);
    l_acc += __shfl_xor(l_acc, 32, 64);
    const float inv = 1.f / l_acc;

    float* op = out + ((size_t)b * SS + qrow) * DD + h * HD;
    #pragma unroll
    for (int ft = 0; ft < 4; ++ft) {
        float4 v = { oacc[ft][0] * inv, oacc[ft][1] * inv,
                     oacc[ft][2] * inv, oacc[ft][3] * inv };
        *(float4*)(op + ft * 16 + g * 4) = v;   // f = ft*16 + g*4 + r, q = qrow
    }
}

extern "C" void kernel_launch(void* const* d_in, const int* in_sizes, int n_in,
                              void* d_out, int out_size, void* d_ws, size_t ws_size,
                              hipStream_t stream) {
    const float* x  = (const float*)d_in[0];
    const float* wq = (const float*)d_in[1];
    float* out = (float*)d_out;
    __hip_bfloat16* q_bf = (__hip_bfloat16*)d_ws;   // 8192*512*2B = 8 MB

    dim3 ggrid(128, 8);
    gemm_kernel<<<ggrid, 256, 0, stream>>>(x, wq, q_bf);
    attn_kernel<<<1024, 256, 0, stream>>>(q_bf, out);
}

// Round 3
// 170.442 us; speedup vs baseline: 7.4574x; 1.1436x over previous
//
#include <hip/hip_runtime.h>
#include <hip/hip_fp16.h>
#include <math.h>

#define SS 2048
#define DD 512
#define NH 8
#define HD 64

typedef __attribute__((ext_vector_type(8))) short frag_ab;   // 8 fp16
typedef __attribute__((ext_vector_type(4))) float frag_cd;   // 4 fp32

static __device__ inline unsigned int pack_h2(float x, float y) {
    __half2 t = __floats2half2_rn(x, y);   // x -> low half
    return *(unsigned int*)&t;
}

// ---------- GEMM: q_h[8192,512] = fp16( x @ Wq ), f16 MFMA, 128x64 tile ----------
__global__ __launch_bounds__(256, 2) void gemm_kernel(const float* __restrict__ x,
                                                      const float* __restrict__ w,
                                                      __half* __restrict__ q) {
    __shared__ __align__(16) unsigned short Ah[128 * 72];  // x tile, row-major [m][k]
    __shared__ __align__(16) unsigned short Bt[64 * 72];   // Wq^T tile [n][k], XOR-swizzled
    const int tid = threadIdx.x;
    const int lane = tid & 63, wv = tid >> 6;
    const int a = lane & 15, g = lane >> 4;
    const int bm = blockIdx.x, bn = blockIdx.y;

    frag_cd acc[2][4] = {};          // [mt][nt]

    const int ar  = tid & 127;       // A staging: row
    const int ach = (tid >> 7) * 32; // A staging: col base
    const int bn0 = (tid & 31) * 2;  // B staging: 2 n-columns
    const int bk0 = (tid >> 5) * 8;  // B staging: 8 k-rows

    for (int k0 = 0; k0 < 512; k0 += 64) {
        __syncthreads();
        {   // stage A: 128x64 fp32 -> fp16
            const float* xp = x + (size_t)(bm * 128 + ar) * 512 + k0 + ach;
            float4 v[8];
            #pragma unroll
            for (int j = 0; j < 8; ++j) v[j] = *(const float4*)(xp + j * 4);
            unsigned int hh[16];
            #pragma unroll
            for (int j = 0; j < 8; ++j) {
                hh[2 * j]     = pack_h2(v[j].x, v[j].y);
                hh[2 * j + 1] = pack_h2(v[j].z, v[j].w);
            }
            #pragma unroll
            for (int j = 0; j < 4; ++j)
                *(uint4*)&Ah[ar * 72 + ach + j * 8] = *(uint4*)&hh[4 * j];
        }
        {   // stage B transposed: Wq[k][n] -> Bt[n][k] (16B chunks XOR-swizzled)
            const float* wp = w + (size_t)(k0 + bk0) * 512 + bn * 64 + bn0;
            float2 v[8];
            #pragma unroll
            for (int j = 0; j < 8; ++j) v[j] = *(const float2*)(wp + (size_t)j * 512);
            unsigned int t0[4], t1[4];
            #pragma unroll
            for (int j = 0; j < 4; ++j) {
                t0[j] = pack_h2(v[2 * j].x, v[2 * j + 1].x);
                t1[j] = pack_h2(v[2 * j].y, v[2 * j + 1].y);
            }
            const int sw = (((bk0 >> 3) ^ ((bn0 >> 1) & 7))) * 8;
            *(uint4*)&Bt[bn0 * 72 + sw]       = *(uint4*)t0;
            *(uint4*)&Bt[(bn0 + 1) * 72 + sw] = *(uint4*)t1;
        }
        __syncthreads();
        #pragma unroll
        for (int kh = 0; kh < 2; ++kh) {
            frag_ab af[2], bf[4];
            #pragma unroll
            for (int mt = 0; mt < 2; ++mt)
                af[mt] = *(const frag_ab*)&Ah[(wv * 32 + mt * 16 + a) * 72 + kh * 32 + g * 8];
            #pragma unroll
            for (int nt = 0; nt < 4; ++nt) {
                const int row = nt * 16 + a;
                bf[nt] = *(const frag_ab*)&Bt[row * 72 + (((kh * 4 + g) ^ ((row >> 1) & 7)) * 8)];
            }
            #pragma unroll
            for (int mt = 0; mt < 2; ++mt)
                #pragma unroll
                for (int nt = 0; nt < 4; ++nt)
                    acc[mt][nt] = __builtin_amdgcn_mfma_f32_16x16x32_f16(af[mt], bf[nt], acc[mt][nt], 0, 0, 0);
        }
    }
    // epilogue: C[m=g*4+r][n=a] -> fp16 q row-major
    #pragma unroll
    for (int mt = 0; mt < 2; ++mt)
        #pragma unroll
        for (int nt = 0; nt < 4; ++nt)
            #pragma unroll
            for (int r = 0; r < 4; ++r) {
                const int m = bm * 128 + wv * 32 + mt * 16 + g * 4 + r;
                const int n = bn * 64 + nt * 16 + a;
                q[(size_t)m * 512 + n] = __float2half_rn(acc[mt][nt][r]);
            }
}

// ---------- Flash attention, f16 MFMA, 32 q per wave ----------
// p = 2^(s*log2e/8 - 8*log2e) = e^(s-8): offset cancels in softmax ratio and keeps
// fp16 P <= ~e^7. Scale 0.125*log2e folded into Q registers (pk_mul once).
__global__ __launch_bounds__(256, 2) void attn_kernel(const __half* __restrict__ qg,
                                                      float* __restrict__ out) {
    __shared__ __align__(16) unsigned short Kt[64 * 72];      // [key][f]
    __shared__ __align__(16) unsigned short Vt[64 * 72];      // [f][key], chunks swizzled
    __shared__ __align__(16) unsigned short Pq[4][32 * 72];   // per-wave [q][key], swizzled

    const int tid = threadIdx.x;
    const int lane = tid & 63, wv = tid >> 6;
    const int a = lane & 15, g = lane >> 4;
    const int bid = blockIdx.x;      // 512 = 16(qt) * 8(h) * 4(b)
    const int qt = bid & 15;
    const int h  = (bid >> 4) & 7;
    const int b  = bid >> 7;

    const unsigned short* qbh = (const unsigned short*)qg + (size_t)b * SS * DD + h * HD;
    const int qrow0 = qt * 128 + wv * 32;

    // Q B-fragments, pre-scaled by 0.125*log2(e)
    frag_ab qf[2][2];
    const __half2 qsc = __float2half2_rn(0.18033688011112042f);
    #pragma unroll
    for (int nt = 0; nt < 2; ++nt)
        #pragma unroll
        for (int kh = 0; kh < 2; ++kh) {
            frag_ab t = *(const frag_ab*)(qbh + (size_t)(qrow0 + nt * 16 + a) * DD + kh * 32 + g * 8);
            __half2* ph = (__half2*)&t;
            #pragma unroll
            for (int i = 0; i < 4; ++i) ph[i] = __hmul2(ph[i], qsc);
            qf[nt][kh] = t;
        }

    frag_cd oacc[4][2] = {};         // [ft][nt]
    float lsum[2] = {0.f, 0.f};

    const int f0 = (tid & 31) * 2;
    const int r0 = (tid >> 5) * 8;
    unsigned short* myP = Pq[wv];

    for (int kb = 0; kb < SS; kb += 64) {
        __syncthreads();
        unsigned int d[8];
        #pragma unroll
        for (int k = 0; k < 8; ++k)
            d[k] = *(const unsigned int*)(qbh + (size_t)(kb + r0 + k) * DD + f0);
        #pragma unroll
        for (int k = 0; k < 8; ++k)
            *(unsigned int*)&Kt[(r0 + k) * 72 + f0] = d[k];
        {   // transposed copy -> Vt, swizzled chunk: floor-rate writes
            unsigned int vlo[4], vhi[4];
            #pragma unroll
            for (int j = 0; j < 4; ++j) {
                vlo[j] = (d[2 * j] & 0xFFFFu) | (d[2 * j + 1] << 16);
                vhi[j] = (d[2 * j] >> 16)     | (d[2 * j + 1] & 0xFFFF0000u);
            }
            const int sw = (((r0 >> 3) ^ ((f0 >> 1) & 7))) * 8;
            *(uint4*)&Vt[f0 * 72 + sw]       = make_uint4(vlo[0], vlo[1], vlo[2], vlo[3]);
            *(uint4*)&Vt[(f0 + 1) * 72 + sw] = make_uint4(vhi[0], vhi[1], vhi[2], vhi[3]);
        }
        __syncthreads();

        // ---- S^T = K . Q^T ----
        frag_cd st[4][2];
        #pragma unroll
        for (int kt = 0; kt < 4; ++kt) {
            const frag_ab ka0 = *(const frag_ab*)&Kt[(kt * 16 + a) * 72 + g * 8];
            const frag_ab ka1 = *(const frag_ab*)&Kt[(kt * 16 + a) * 72 + 32 + g * 8];
            #pragma unroll
            for (int nt = 0; nt < 2; ++nt) {
                frag_cd c = {};
                c = __builtin_amdgcn_mfma_f32_16x16x32_f16(ka0, qf[nt][0], c, 0, 0, 0);
                c = __builtin_amdgcn_mfma_f32_16x16x32_f16(ka1, qf[nt][1], c, 0, 0, 0);
                st[kt][nt] = c;
            }
        }
        // ---- exp2 (offset) + stage P (wave-private, no barrier) ----
        #pragma unroll
        for (int nt = 0; nt < 2; ++nt) {
            const int prow = nt * 16 + a;
            #pragma unroll
            for (int kt = 0; kt < 4; ++kt) {
                const float p0 = __builtin_amdgcn_exp2f(st[kt][nt][0] - 11.541560327111707f);
                const float p1 = __builtin_amdgcn_exp2f(st[kt][nt][1] - 11.541560327111707f);
                const float p2 = __builtin_amdgcn_exp2f(st[kt][nt][2] - 11.541560327111707f);
                const float p3 = __builtin_amdgcn_exp2f(st[kt][nt][3] - 11.541560327111707f);
                lsum[nt] += (p0 + p1) + (p2 + p3);
                uint2 pw = { pack_h2(p0, p1), pack_h2(p2, p3) };
                const int chunk = 2 * kt + (g >> 1);
                *(uint2*)&myP[prow * 72 + ((chunk ^ (prow & 7)) * 8) + (g & 1) * 4] = pw;
            }
        }
        // ---- O^T += V^T . P^T ----
        #pragma unroll
        for (int kh = 0; kh < 2; ++kh) {
            frag_ab va[4], pb[2];
            #pragma unroll
            for (int ft = 0; ft < 4; ++ft) {
                const int row = ft * 16 + a;
                va[ft] = *(const frag_ab*)&Vt[row * 72 + (((kh * 4 + g) ^ ((row >> 1) & 7)) * 8)];
            }
            #pragma unroll
            for (int nt = 0; nt < 2; ++nt) {
                const int row = nt * 16 + a;
                pb[nt] = *(const frag_ab*)&myP[row * 72 + (((kh * 4 + g) ^ (row & 7)) * 8)];
            }
            #pragma unroll
            for (int ft = 0; ft < 4; ++ft)
                #pragma unroll
                for (int nt = 0; nt < 2; ++nt)
                    oacc[ft][nt] = __builtin_amdgcn_mfma_f32_16x16x32_f16(va[ft], pb[nt], oacc[ft][nt], 0, 0, 0);
        }
    }

    #pragma unroll
    for (int nt = 0; nt < 2; ++nt) {
        float l = lsum[nt];
        l += __shfl_xor(l, 16, 64);
        l += __shfl_xor(l, 32, 64);
        const float inv = 1.f / l;
        float* op = out + ((size_t)b * SS + qrow0 + nt * 16 + a) * DD + h * HD;
        #pragma unroll
        for (int ft = 0; ft < 4; ++ft) {
            float4 v = { oacc[ft][nt][0] * inv, oacc[ft][nt][1] * inv,
                         oacc[ft][nt][2] * inv, oacc[ft][nt][3] * inv };
            *(float4*)(op + ft * 16 + g * 4) = v;
        }
    }
}

extern "C" void kernel_launch(void* const* d_in, const int* in_sizes, int n_in,
                              void* d_out, int out_size, void* d_ws, size_t ws_size,
                              hipStream_t stream) {
    const float* x  = (const float*)d_in[0];
    const float* wq = (const float*)d_in[1];
    float* out = (float*)d_out;
    __half* q_h = (__half*)d_ws;     // 8192*512*2B = 8 MB

    dim3 ggrid(64, 8);
    gemm_kernel<<<ggrid, 256, 0, stream>>>(x, wq, q_h);
    attn_kernel<<<512, 256, 0, stream>>>(q_h, out);
}

// Round 5
// 140.842 us; speedup vs baseline: 9.0247x; 1.2102x over previous
//
#include <hip/hip_runtime.h>
#include <hip/hip_fp16.h>
#include <math.h>

#define SS 2048
#define DD 512
#define NH 8
#define HD 64

typedef __attribute__((ext_vector_type(8))) short frag_ab;   // 8 fp16
typedef __attribute__((ext_vector_type(4))) float frag_cd;   // 4 fp32

static __device__ inline unsigned int pack_h2(float x, float y) {
    __half2 t = __floats2half2_rn(x, y);   // x -> low half
    return *(unsigned int*)&t;
}

// ---------- wt[n][k] = fp16(Wq[k][n]) : 512x512 pre-transpose ----------
__global__ __launch_bounds__(256) void wt_kernel(const float* __restrict__ w,
                                                 unsigned short* __restrict__ wt) {
    __shared__ float T[64][69];   // 69-pad: transposed b32 reads land 2/bank
    const int tid = threadIdx.x;
    const int tk = blockIdx.x, tn = blockIdx.y;
    #pragma unroll
    for (int p = 0; p < 4; ++p) {
        const int r = (tid >> 4) + p * 16;
        const int c4 = (tid & 15) * 4;
        float4 v = *(const float4*)(w + (size_t)(tk * 64 + r) * 512 + tn * 64 + c4);
        T[r][c4] = v.x; T[r][c4 + 1] = v.y; T[r][c4 + 2] = v.z; T[r][c4 + 3] = v.w;
    }
    __syncthreads();
    #pragma unroll
    for (int p = 0; p < 2; ++p) {
        const int rn = (tid >> 3) + p * 32;       // n within tile
        const int ck = (tid & 7) * 8;             // k within tile
        unsigned int o[4];
        #pragma unroll
        for (int j = 0; j < 4; ++j)
            o[j] = pack_h2(T[ck + 2 * j][rn], T[ck + 2 * j + 1][rn]);
        *(uint4*)(wt + (size_t)(tn * 64 + rn) * 512 + tk * 64 + ck) = *(uint4*)o;
    }
}

// ---------- GEMM: q_h[8192,512] = fp16( x @ Wq ), A via LDS, B direct from wt ----------
__global__ __launch_bounds__(256, 2) void gemm_kernel(const float* __restrict__ x,
                                                      const unsigned short* __restrict__ wt,
                                                      unsigned short* __restrict__ q) {
    __shared__ __align__(16) unsigned short Ah[64 * 72];   // [m][k], 72-short rows
    const int tid = threadIdx.x;
    const int lane = tid & 63, wv = tid >> 6;
    const int a = lane & 15, g = lane >> 4;
    const int bm = blockIdx.x, bn = blockIdx.y;   // M-tile 64, N-tile 128

    frag_cd acc[4][2] = {};
    const int sr  = tid >> 4;         // staging row group
    const int sc4 = (tid & 15) * 4;   // staging col: 16 lanes cover 256B/row

    for (int k0 = 0; k0 < 512; k0 += 64) {
        __syncthreads();
        #pragma unroll
        for (int p = 0; p < 4; ++p) {
            const int r = sr + p * 16;
            float4 v = *(const float4*)(x + (size_t)(bm * 64 + r) * 512 + k0 + sc4);
            uint2 h = { pack_h2(v.x, v.y), pack_h2(v.z, v.w) };
            *(uint2*)&Ah[r * 72 + sc4] = h;
        }
        __syncthreads();
        #pragma unroll
        for (int kh = 0; kh < 2; ++kh) {
            frag_ab af[4], bf[2];
            #pragma unroll
            for (int nt = 0; nt < 2; ++nt)   // B-frags straight from L2-resident wt
                bf[nt] = *(const frag_ab*)(wt + (size_t)(bn * 128 + wv * 32 + nt * 16 + a) * 512
                                              + k0 + kh * 32 + g * 8);
            #pragma unroll
            for (int mt = 0; mt < 4; ++mt)
                af[mt] = *(const frag_ab*)&Ah[(mt * 16 + a) * 72 + kh * 32 + g * 8];
            #pragma unroll
            for (int mt = 0; mt < 4; ++mt)
                #pragma unroll
                for (int nt = 0; nt < 2; ++nt)
                    acc[mt][nt] = __builtin_amdgcn_mfma_f32_16x16x32_f16(af[mt], bf[nt], acc[mt][nt], 0, 0, 0);
        }
    }
    #pragma unroll
    for (int mt = 0; mt < 4; ++mt)
        #pragma unroll
        for (int nt = 0; nt < 2; ++nt)
            #pragma unroll
            for (int r = 0; r < 4; ++r) {
                const int m = bm * 64 + mt * 16 + g * 4 + r;
                const int n = bn * 128 + wv * 32 + nt * 16 + a;
                __half hv = __float2half_rn(acc[mt][nt][r]);
                q[(size_t)m * 512 + n] = *(unsigned short*)&hv;
            }
}

// ---------- stage one 64-key K/V tile (natural layout — floor-rate by quad math) ----------
static __device__ inline void stage_kv(unsigned short* Kb, unsigned short* Vb,
                                       const unsigned int* d, int r0, int f0) {
    #pragma unroll
    for (int k = 0; k < 8; ++k)
        *(unsigned int*)&Kb[(r0 + k) * 72 + f0] = d[k];
    unsigned int vlo[4], vhi[4];
    #pragma unroll
    for (int j = 0; j < 4; ++j) {
        vlo[j] = (d[2 * j] & 0xFFFFu) | (d[2 * j + 1] << 16);
        vhi[j] = (d[2 * j] >> 16)     | (d[2 * j + 1] & 0xFFFF0000u);
    }
    *(uint4*)&Vb[f0 * 72 + r0]       = make_uint4(vlo[0], vlo[1], vlo[2], vlo[3]);
    *(uint4*)&Vb[(f0 + 1) * 72 + r0] = make_uint4(vhi[0], vhi[1], vhi[2], vhi[3]);
}

// ---------- Flash attention: f16 MFMA, 32 q/wave, double-buffered K/V ----------
__global__ __launch_bounds__(256, 2) void attn_kernel(const __half* __restrict__ qg,
                                                      float* __restrict__ out) {
    __shared__ __align__(16) unsigned short Kt[2][64 * 72];   // [key][f]
    __shared__ __align__(16) unsigned short Vt[2][64 * 72];   // [f][key]
    __shared__ __align__(16) unsigned short Pq[4][32 * 72];   // per-wave [q][key]

    const int tid = threadIdx.x;
    const int lane = tid & 63, wv = tid >> 6;
    const int a = lane & 15, g = lane >> 4;
    const int bid = blockIdx.x;       // 512 = 16(qt) * 8(h) * 4(b)
    const int qt = bid & 15;
    const int h  = (bid >> 4) & 7;
    const int b  = bid >> 7;

    const unsigned short* qbh = (const unsigned short*)qg + (size_t)b * SS * DD + h * HD;
    const int qrow0 = qt * 128 + wv * 32;

    // Q B-fragments, pre-scaled by 0.125*log2(e)
    frag_ab qf[2][2];
    const __half2 qsc = __float2half2_rn(0.18033688011112042f);
    #pragma unroll
    for (int nt = 0; nt < 2; ++nt)
        #pragma unroll
        for (int kh = 0; kh < 2; ++kh) {
            frag_ab t = *(const frag_ab*)(qbh + (size_t)(qrow0 + nt * 16 + a) * DD + kh * 32 + g * 8);
            __half2* ph = (__half2*)&t;
            #pragma unroll
            for (int i = 0; i < 4; ++i) ph[i] = __hmul2(ph[i], qsc);
            qf[nt][kh] = t;
        }

    frag_cd oacc[4][2] = {};          // [ft][nt] O^T tiles
    float lsum[2] = {0.f, 0.f};

    const int f0 = (tid & 31) * 2;
    const int r0 = (tid >> 5) * 8;
    unsigned short* myP = Pq[wv];

    {   // prologue: stage tile 0 into buffer 0
        unsigned int d[8];
        #pragma unroll
        for (int k = 0; k < 8; ++k)
            d[k] = *(const unsigned int*)(qbh + (size_t)(r0 + k) * DD + f0);
        stage_kv(Kt[0], Vt[0], d, r0, f0);
    }

    for (int it = 0; it < 32; ++it) {
        const int cur = it & 1;
        __syncthreads();              // buf[cur] ready; buf[cur^1] fully consumed

        unsigned int dn[8];
        const bool more = (it + 1 < 32);
        if (more) {
            const int kb = (it + 1) * 64;
            #pragma unroll
            for (int k = 0; k < 8; ++k)
                dn[k] = *(const unsigned int*)(qbh + (size_t)(kb + r0 + k) * DD + f0);
        }

        const unsigned short* Kc = Kt[cur];
        const unsigned short* Vc = Vt[cur];

        // ---- S^T = K . Q^T ----
        frag_cd st[4][2];
        #pragma unroll
        for (int kt = 0; kt < 4; ++kt) {
            const frag_ab ka0 = *(const frag_ab*)&Kc[(kt * 16 + a) * 72 + g * 8];
            const frag_ab ka1 = *(const frag_ab*)&Kc[(kt * 16 + a) * 72 + 32 + g * 8];
            #pragma unroll
            for (int nt = 0; nt < 2; ++nt) {
                frag_cd c = {};
                c = __builtin_amdgcn_mfma_f32_16x16x32_f16(ka0, qf[nt][0], c, 0, 0, 0);
                c = __builtin_amdgcn_mfma_f32_16x16x32_f16(ka1, qf[nt][1], c, 0, 0, 0);
                st[kt][nt] = c;
            }
        }
        // ---- p = 2^(s' - 8*log2e), stage P (wave-private, natural layout) ----
        #pragma unroll
        for (int nt = 0; nt < 2; ++nt) {
            const int prow = nt * 16 + a;
            #pragma unroll
            for (int kt = 0; kt < 4; ++kt) {
                const float p0 = __builtin_amdgcn_exp2f(st[kt][nt][0] - 11.541560327111707f);
                const float p1 = __builtin_amdgcn_exp2f(st[kt][nt][1] - 11.541560327111707f);
                const float p2 = __builtin_amdgcn_exp2f(st[kt][nt][2] - 11.541560327111707f);
                const float p3 = __builtin_amdgcn_exp2f(st[kt][nt][3] - 11.541560327111707f);
                lsum[nt] += (p0 + p1) + (p2 + p3);
                uint2 pw = { pack_h2(p0, p1), pack_h2(p2, p3) };
                *(uint2*)&myP[prow * 72 + kt * 16 + g * 4] = pw;
            }
        }
        // ---- O^T += V^T . P^T ----
        #pragma unroll
        for (int kh = 0; kh < 2; ++kh) {
            frag_ab va[4], pb[2];
            #pragma unroll
            for (int ft = 0; ft < 4; ++ft)
                va[ft] = *(const frag_ab*)&Vc[(ft * 16 + a) * 72 + kh * 32 + g * 8];
            #pragma unroll
            for (int nt = 0; nt < 2; ++nt)
                pb[nt] = *(const frag_ab*)&myP[(nt * 16 + a) * 72 + kh * 32 + g * 8];
            #pragma unroll
            for (int ft = 0; ft < 4; ++ft)
                #pragma unroll
                for (int nt = 0; nt < 2; ++nt)
                    oacc[ft][nt] = __builtin_amdgcn_mfma_f32_16x16x32_f16(va[ft], pb[nt], oacc[ft][nt], 0, 0, 0);
        }
        // ---- write next tile into the other buffer (safe: barrier at next iter top) ----
        if (more)
            stage_kv(Kt[cur ^ 1], Vt[cur ^ 1], dn, r0, f0);
    }

    #pragma unroll
    for (int nt = 0; nt < 2; ++nt) {
        float l = lsum[nt];
        l += __shfl_xor(l, 16, 64);
        l += __shfl_xor(l, 32, 64);
        const float inv = 1.f / l;
        float* op = out + ((size_t)b * SS + qrow0 + nt * 16 + a) * DD + h * HD;
        #pragma unroll
        for (int ft = 0; ft < 4; ++ft) {
            float4 v = { oacc[ft][nt][0] * inv, oacc[ft][nt][1] * inv,
                         oacc[ft][nt][2] * inv, oacc[ft][nt][3] * inv };
            *(float4*)(op + ft * 16 + g * 4) = v;
        }
    }
}

extern "C" void kernel_launch(void* const* d_in, const int* in_sizes, int n_in,
                              void* d_out, int out_size, void* d_ws, size_t ws_size,
                              hipStream_t stream) {
    const float* x  = (const float*)d_in[0];
    const float* wq = (const float*)d_in[1];
    float* out = (float*)d_out;
    unsigned short* q_h = (unsigned short*)d_ws;                        // 8 MB
    unsigned short* wt  = (unsigned short*)((char*)d_ws + (8u << 20));  // +512 KB

    dim3 tgrid(8, 8);
    wt_kernel<<<tgrid, 256, 0, stream>>>(wq, wt);
    dim3 ggrid(128, 4);
    gemm_kernel<<<ggrid, 256, 0, stream>>>(x, wt, q_h);
    attn_kernel<<<512, 256, 0, stream>>>((const __half*)q_h, out);
}